// Round 9
// baseline (388.067 us; speedup 1.0000x reference)
//
#include <hip/hip_runtime.h>
#include <hip/hip_bf16.h>
#include <stdint.h>

#define NN 100000
#define NE 600000
#define ND 128
#define ED 32
#define HID 128
#define SCANB 391  // ceil(NN/256)

using short8 = __attribute__((ext_vector_type(8))) short;
using f32x4  = __attribute__((ext_vector_type(4))) float;

// ---------- bf16 helpers (manual RNE, deterministic) ----------
__device__ __forceinline__ uint32_t f2bf(float f) {
  uint32_t u = __float_as_uint(f);
  return (u + 0x7FFFu + ((u >> 16) & 1u)) >> 16;
}
__device__ __forceinline__ short8 pack8(float4 a, float4 b) {
  short8 s;
  s[0] = (short)f2bf(a.x); s[1] = (short)f2bf(a.y);
  s[2] = (short)f2bf(a.z); s[3] = (short)f2bf(a.w);
  s[4] = (short)f2bf(b.x); s[5] = (short)f2bf(b.y);
  s[6] = (short)f2bf(b.z); s[7] = (short)f2bf(b.w);
  return s;
}

// ---------- weight pre-pack: frag-ordered bf16 ----------
__global__ __launch_bounds__(256) void k_prep(
    const float* __restrict__ W1, const float* __restrict__ W2,
    const float* __restrict__ uW1, const float* __restrict__ uW2,
    short* __restrict__ W1p, short* __restrict__ W2p,
    short* __restrict__ U1p, short* __restrict__ U2p) {
  int o = blockIdx.x * 256 + threadIdx.x;
  const float* src; short* dst; int rel;
  if (o < 36864)      { rel = o;         src = W1;  dst = W1p; }
  else if (o < 53248) { rel = o - 36864; src = W2;  dst = W2p; }
  else if (o < 86016) { rel = o - 53248; src = uW1; dst = U1p; }
  else                { rel = o - 86016; src = uW2; dst = U2p; }
  int j = rel & 7, c16 = (rel >> 3) & 15, g = (rel >> 7) & 3, nt = (rel >> 9) & 7, c = rel >> 12;
  int k = c * 32 + g * 8 + j, n = nt * 16 + c16;
  dst[rel] = (short)f2bf(src[k * 128 + n]);
}

// ---------- node features fp32 -> bf16 ----------
__global__ __launch_bounds__(256) void k_prep_nf(const float* __restrict__ nf,
                                                 short* __restrict__ nfb) {
  const int total = NN * ND / 8;
  for (int u = blockIdx.x * 256 + threadIdx.x; u < total; u += gridDim.x * 256) {
    const float* s = nf + (size_t)u * 8;
    float4 v0 = *(const float4*)s, v1 = *(const float4*)(s + 4);
    *(short8*)(nfb + (size_t)u * 8) = pack8(v0, v1);
  }
}

// ---------- edge MLP via MFMA: 128-row tile, 3 blocks/CU ----------
__global__ __launch_bounds__(256, 3) void k_edge_mfma(
    const short* __restrict__ nfb, const float* __restrict__ ef,
    const short* __restrict__ W1p, const float* __restrict__ b1,
    const short* __restrict__ W2p, const float* __restrict__ b2,
    const float* __restrict__ aW, const int* __restrict__ ei,
    uint16_t* __restrict__ msg, float* __restrict__ logits) {
  __shared__ __align__(16) short sA[128 * 40];   // 10240 B
  __shared__ __align__(16) short sB[4096];       //  8192 B
  __shared__ __align__(16) short sH[128 * 136];  // 34816 B
  __shared__ int sIdx[256];                      //  1024 B  -> 54272 total

  const int tid = threadIdx.x;
  const int wv = tid >> 6, ln = tid & 63, cr = ln & 15, gp = ln >> 4;
  const int e0 = blockIdx.x * 128;  // grid 4688; last block: 64 valid rows
  const int wrow = wv * 32;

  if (tid < 128) {
    int e = e0 + tid; if (e >= NE) e = NE - 1;
    sIdx[tid] = ei[e];
    sIdx[128 + tid] = ei[NE + e];
  }

  float bia[8], aWr[8], bia2[8];
#pragma unroll
  for (int nt = 0; nt < 8; ++nt) {
    bia[nt] = b1[nt * 16 + cr];
    bia2[nt] = b2[nt * 16 + cr];
    aWr[nt] = aW[nt * 16 + cr];
  }
  f32x4 acc[2][8];
#pragma unroll
  for (int mt = 0; mt < 2; ++mt)
#pragma unroll
    for (int nt = 0; nt < 8; ++nt)
      acc[mt][nt] = (f32x4){bia[nt], bia[nt], bia[nt], bia[nt]};
  __syncthreads();

  // layer 1: K = 288 (chunks 0-3: nfb[row], 4-7: nfb[col], 8: ef)
  for (int c = 0; c < 9; ++c) {
#pragma unroll
    for (int it = 0; it < 2; ++it) {
      int task = it * 256 + tid;
      int row = task >> 2, k8 = (task & 3) * 8;
      if (c < 8) {
        const short* src = nfb + (size_t)sIdx[(c < 4 ? 0 : 128) + row] * ND +
                           (c & 3) * 32 + k8;
        *(short8*)&sA[row * 40 + k8] = *(const short8*)src;
      } else {
        int e = e0 + row; if (e >= NE) e = NE - 1;
        const float* src = ef + (size_t)e * ED + k8;
        float4 v0 = *(const float4*)src, v1 = *(const float4*)(src + 4);
        *(short8*)&sA[row * 40 + k8] = pack8(v0, v1);
      }
    }
    {
      const short8* wsrc = (const short8*)(W1p + c * 4096);
      short8 t0 = wsrc[tid], t1 = wsrc[tid + 256];
      ((short8*)sB)[tid] = t0; ((short8*)sB)[tid + 256] = t1;
    }
    __syncthreads();
    short8 af0 = *(const short8*)&sA[(wrow + cr) * 40 + gp * 8];
    short8 af1 = *(const short8*)&sA[(wrow + 16 + cr) * 40 + gp * 8];
#pragma unroll
    for (int nt = 0; nt < 8; ++nt) {
      short8 bfr = *(const short8*)&sB[(nt * 4 + gp) * 128 + cr * 8];
      acc[0][nt] = __builtin_amdgcn_mfma_f32_16x16x32_bf16(af0, bfr, acc[0][nt], 0, 0, 0);
      acc[1][nt] = __builtin_amdgcn_mfma_f32_16x16x32_bf16(af1, bfr, acc[1][nt], 0, 0, 0);
    }
    __syncthreads();
  }

  // relu -> sH (bf16)
#pragma unroll
  for (int mt = 0; mt < 2; ++mt)
#pragma unroll
    for (int nt = 0; nt < 8; ++nt)
#pragma unroll
      for (int rr = 0; rr < 4; ++rr)
        sH[(wrow + mt * 16 + gp * 4 + rr) * 136 + nt * 16 + cr] =
            (short)f2bf(fmaxf(acc[mt][nt][rr], 0.f));
  __syncthreads();

  // layer 2: K = 128
  f32x4 acc2[2][8];
#pragma unroll
  for (int mt = 0; mt < 2; ++mt)
#pragma unroll
    for (int nt = 0; nt < 8; ++nt)
      acc2[mt][nt] = (f32x4){bia2[nt], bia2[nt], bia2[nt], bia2[nt]};
  for (int c2 = 0; c2 < 4; ++c2) {
    {
      const short8* wsrc = (const short8*)(W2p + c2 * 4096);
      short8 t0 = wsrc[tid], t1 = wsrc[tid + 256];
      ((short8*)sB)[tid] = t0; ((short8*)sB)[tid + 256] = t1;
    }
    __syncthreads();
    short8 af0 = *(const short8*)&sH[(wrow + cr) * 136 + c2 * 32 + gp * 8];
    short8 af1 = *(const short8*)&sH[(wrow + 16 + cr) * 136 + c2 * 32 + gp * 8];
#pragma unroll
    for (int nt = 0; nt < 8; ++nt) {
      short8 bfr = *(const short8*)&sB[(nt * 4 + gp) * 128 + cr * 8];
      acc2[0][nt] = __builtin_amdgcn_mfma_f32_16x16x32_bf16(af0, bfr, acc2[0][nt], 0, 0, 0);
      acc2[1][nt] = __builtin_amdgcn_mfma_f32_16x16x32_bf16(af1, bfr, acc2[1][nt], 0, 0, 0);
    }
    __syncthreads();
  }

  // attention logits (reduce over the 16 col-lanes)
#pragma unroll
  for (int mt = 0; mt < 2; ++mt)
#pragma unroll
    for (int rr = 0; rr < 4; ++rr) {
      float p = 0.f;
#pragma unroll
      for (int nt = 0; nt < 8; ++nt) p += acc2[mt][nt][rr] * aWr[nt];
      p += __shfl_xor(p, 1, 64);
      p += __shfl_xor(p, 2, 64);
      p += __shfl_xor(p, 4, 64);
      p += __shfl_xor(p, 8, 64);
      int e = e0 + wrow + mt * 16 + gp * 4 + rr;
      if (cr == 0 && e < NE) logits[e] = p;
    }

  // messages -> sH (bf16) -> coalesced global write (guarded for tail)
#pragma unroll
  for (int mt = 0; mt < 2; ++mt)
#pragma unroll
    for (int nt = 0; nt < 8; ++nt)
#pragma unroll
      for (int rr = 0; rr < 4; ++rr)
        sH[(wrow + mt * 16 + gp * 4 + rr) * 136 + nt * 16 + cr] =
            (short)f2bf(acc2[mt][nt][rr]);
  __syncthreads();
#pragma unroll
  for (int it = 0; it < 8; ++it) {
    int row = it * 16 + (tid >> 4), o8 = (tid & 15) * 8;
    int e = e0 + row;
    if (e < NE)
      *(short8*)(msg + (size_t)e * HID + o8) = *(const short8*)&sH[row * 136 + o8];
  }
}

// ---------- node update MLP via MFMA (+ residual): 128-tile, 3 blocks/CU ----------
__global__ __launch_bounds__(256, 3) void k_node_mfma(
    const float* __restrict__ nf, const short* __restrict__ nfb,
    const float* __restrict__ agg,
    const short* __restrict__ U1p, const float* __restrict__ b1,
    const short* __restrict__ U2p, const float* __restrict__ b2,
    float* __restrict__ out) {
  __shared__ __align__(16) short sA[128 * 40];
  __shared__ __align__(16) short sB[4096];
  __shared__ __align__(16) short sH[128 * 136];  // 53248 B total

  const int tid = threadIdx.x;
  const int wv = tid >> 6, ln = tid & 63, cr = ln & 15, gp = ln >> 4;
  const int n0 = blockIdx.x * 128;
  const int wrow = wv * 32;

  float bia[8], bia2[8];
#pragma unroll
  for (int nt = 0; nt < 8; ++nt) {
    bia[nt] = b1[nt * 16 + cr];
    bia2[nt] = b2[nt * 16 + cr];
  }
  f32x4 acc[2][8];
#pragma unroll
  for (int mt = 0; mt < 2; ++mt)
#pragma unroll
    for (int nt = 0; nt < 8; ++nt)
      acc[mt][nt] = (f32x4){bia[nt], bia[nt], bia[nt], bia[nt]};

  // layer 1: K = 256 (chunks 0-3: nfb bf16 direct, 4-7: agg fp32 -> pack)
  for (int c = 0; c < 8; ++c) {
#pragma unroll
    for (int it = 0; it < 2; ++it) {
      int task = it * 256 + tid;
      int row = task >> 2, k8 = (task & 3) * 8;
      int n = n0 + row; if (n >= NN) n = NN - 1;
      if (c < 4) {
        *(short8*)&sA[row * 40 + k8] =
            *(const short8*)(nfb + (size_t)n * ND + c * 32 + k8);
      } else {
        const float* src = agg + (size_t)n * ND + (c - 4) * 32 + k8;
        float4 v0 = *(const float4*)src, v1 = *(const float4*)(src + 4);
        *(short8*)&sA[row * 40 + k8] = pack8(v0, v1);
      }
    }
    {
      const short8* wsrc = (const short8*)(U1p + c * 4096);
      short8 t0 = wsrc[tid], t1 = wsrc[tid + 256];
      ((short8*)sB)[tid] = t0; ((short8*)sB)[tid + 256] = t1;
    }
    __syncthreads();
    short8 af0 = *(const short8*)&sA[(wrow + cr) * 40 + gp * 8];
    short8 af1 = *(const short8*)&sA[(wrow + 16 + cr) * 40 + gp * 8];
#pragma unroll
    for (int nt = 0; nt < 8; ++nt) {
      short8 bfr = *(const short8*)&sB[(nt * 4 + gp) * 128 + cr * 8];
      acc[0][nt] = __builtin_amdgcn_mfma_f32_16x16x32_bf16(af0, bfr, acc[0][nt], 0, 0, 0);
      acc[1][nt] = __builtin_amdgcn_mfma_f32_16x16x32_bf16(af1, bfr, acc[1][nt], 0, 0, 0);
    }
    __syncthreads();
  }

#pragma unroll
  for (int mt = 0; mt < 2; ++mt)
#pragma unroll
    for (int nt = 0; nt < 8; ++nt)
#pragma unroll
      for (int rr = 0; rr < 4; ++rr)
        sH[(wrow + mt * 16 + gp * 4 + rr) * 136 + nt * 16 + cr] =
            (short)f2bf(fmaxf(acc[mt][nt][rr], 0.f));
  __syncthreads();

  f32x4 acc2[2][8];
#pragma unroll
  for (int mt = 0; mt < 2; ++mt)
#pragma unroll
    for (int nt = 0; nt < 8; ++nt)
      acc2[mt][nt] = (f32x4){bia2[nt], bia2[nt], bia2[nt], bia2[nt]};
  for (int c2 = 0; c2 < 4; ++c2) {
    {
      const short8* wsrc = (const short8*)(U2p + c2 * 4096);
      short8 t0 = wsrc[tid], t1 = wsrc[tid + 256];
      ((short8*)sB)[tid] = t0; ((short8*)sB)[tid + 256] = t1;
    }
    __syncthreads();
    short8 af0 = *(const short8*)&sH[(wrow + cr) * 136 + c2 * 32 + gp * 8];
    short8 af1 = *(const short8*)&sH[(wrow + 16 + cr) * 136 + c2 * 32 + gp * 8];
#pragma unroll
    for (int nt = 0; nt < 8; ++nt) {
      short8 bfr = *(const short8*)&sB[(nt * 4 + gp) * 128 + cr * 8];
      acc2[0][nt] = __builtin_amdgcn_mfma_f32_16x16x32_bf16(af0, bfr, acc2[0][nt], 0, 0, 0);
      acc2[1][nt] = __builtin_amdgcn_mfma_f32_16x16x32_bf16(af1, bfr, acc2[1][nt], 0, 0, 0);
    }
    __syncthreads();
  }

  // residual + store
#pragma unroll
  for (int mt = 0; mt < 2; ++mt)
#pragma unroll
    for (int rr = 0; rr < 4; ++rr) {
      int n = n0 + wrow + mt * 16 + gp * 4 + rr;
      if (n < NN) {
#pragma unroll
        for (int nt = 0; nt < 8; ++nt) {
          int col = nt * 16 + cr;
          out[(size_t)n * ND + col] = acc2[mt][nt][rr] + nf[(size_t)n * ND + col];
        }
      }
    }
}

// ---------- fused online softmax reductions: (max,sum) pairs ----------
__device__ __forceinline__ void ms_combine(float& m, float& s, float m2, float s2) {
  float M = fmaxf(m, m2);
  s = s * expf(m - M) + s2 * expf(m2 - M);
  m = M;
}
__device__ __forceinline__ void ms_block_reduce(float& m, float& s) {
#pragma unroll
  for (int o = 1; o < 64; o <<= 1) {
    float m2 = __shfl_xor(m, o, 64), s2 = __shfl_xor(s, o, 64);
    ms_combine(m, s, m2, s2);
  }
  __shared__ float sm[4], ss[4];
  if ((threadIdx.x & 63) == 0) { sm[threadIdx.x >> 6] = m; ss[threadIdx.x >> 6] = s; }
  __syncthreads();
  m = sm[0]; s = ss[0];
  ms_combine(m, s, sm[1], ss[1]);
  ms_combine(m, s, sm[2], ss[2]);
  ms_combine(m, s, sm[3], ss[3]);
}
__global__ __launch_bounds__(256) void k_red_p(const float* __restrict__ logits,
                                               float* __restrict__ pmax,
                                               float* __restrict__ psum) {
  float m = -3.402823466e38f, s = 0.f;
  for (int i = blockIdx.x * 256 + threadIdx.x; i < NE; i += 1024 * 256) {
    float l = logits[i];
    if (l <= m) s += expf(l - m);
    else { s = s * expf(m - l) + 1.f; m = l; }
  }
  ms_block_reduce(m, s);
  if (threadIdx.x == 0) { pmax[blockIdx.x] = m; psum[blockIdx.x] = s; }
}
__global__ __launch_bounds__(256) void k_red_f(const float* __restrict__ pmax,
                                               const float* __restrict__ psum,
                                               float* __restrict__ red) {
  float m = pmax[threadIdx.x], s = psum[threadIdx.x];
  ms_combine(m, s, pmax[threadIdx.x + 256], psum[threadIdx.x + 256]);
  ms_combine(m, s, pmax[threadIdx.x + 512], psum[threadIdx.x + 512]);
  ms_combine(m, s, pmax[threadIdx.x + 768], psum[threadIdx.x + 768]);
  ms_block_reduce(m, s);
  if (threadIdx.x == 0) { red[0] = m; red[1] = 1.0f / s; }
}

// ---------- CSR build ----------
__global__ __launch_bounds__(256) void k_zero_cnt(int* __restrict__ cnt) {
  int i = blockIdx.x * 256 + threadIdx.x;
  if (i < NN) cnt[i] = 0;
}
__global__ __launch_bounds__(256) void k_hist(const int* __restrict__ ei,
                                              int* __restrict__ cnt) {
  int e = blockIdx.x * 256 + threadIdx.x;
  if (e < NE) atomicAdd(&cnt[ei[NE + e]], 1);
}
__global__ __launch_bounds__(256) void k_scan_bsum(const int* __restrict__ cnt,
                                                   int* __restrict__ bsum) {
  int i = blockIdx.x * 256 + threadIdx.x;
  int v = (i < NN) ? cnt[i] : 0;
#pragma unroll
  for (int s = 1; s < 64; s <<= 1) v += __shfl_xor(v, s, 64);
  __shared__ int sv[4];
  if ((threadIdx.x & 63) == 0) sv[threadIdx.x >> 6] = v;
  __syncthreads();
  if (threadIdx.x == 0) bsum[blockIdx.x] = sv[0] + sv[1] + sv[2] + sv[3];
}
__global__ __launch_bounds__(512) void k_scan_boff(const int* __restrict__ bsum,
                                                   int* __restrict__ boff,
                                                   int* __restrict__ rowptr) {
  __shared__ int s[512];
  int t = threadIdx.x;
  int v = (t < SCANB) ? bsum[t] : 0;
  s[t] = v;
  __syncthreads();
  for (int off = 1; off < 512; off <<= 1) {
    int u = (t >= off) ? s[t - off] : 0;
    __syncthreads();
    s[t] += u;
    __syncthreads();
  }
  if (t < SCANB) boff[t] = s[t] - v;  // exclusive
  if (t == 0) rowptr[NN] = NE;
}
__global__ __launch_bounds__(256) void k_scan_final(int* __restrict__ cnt,
                                                    const int* __restrict__ boff,
                                                    int* __restrict__ rowptr) {
  __shared__ int s[256];
  int b = blockIdx.x, t = threadIdx.x, i = b * 256 + t;
  int v = (i < NN) ? cnt[i] : 0;
  s[t] = v;
  __syncthreads();
  for (int off = 1; off < 256; off <<= 1) {
    int u = (t >= off) ? s[t - off] : 0;
    __syncthreads();
    s[t] += u;
    __syncthreads();
  }
  int excl = s[t] - v + boff[b];
  if (i < NN) { rowptr[i] = excl; cnt[i] = excl; }  // cnt becomes the fill cursor
}
__global__ __launch_bounds__(256) void k_fill(const int* __restrict__ ei,
                                              int* __restrict__ cursor,
                                              int* __restrict__ eid) {
  int e = blockIdx.x * 256 + threadIdx.x;
  if (e >= NE) return;
  int c = ei[NE + e];
  int pos = atomicAdd(&cursor[c], 1);
  eid[pos] = e;
}

// ---------- CSR gather-aggregate (weights fused): one wave per node ----------
__global__ __launch_bounds__(256) void k_agg(
    const uint16_t* __restrict__ msg, const float* __restrict__ logits,
    const int* __restrict__ rowptr, const int* __restrict__ eid,
    const float* __restrict__ red, float* __restrict__ out) {
  int n = blockIdx.x * 4 + (threadIdx.x >> 6);
  int lane = threadIdx.x & 63;
  if (n >= NN) return;
  float gm = red[0], inv = red[1];
  int i0 = rowptr[n], i1 = rowptr[n + 1];
  float a0 = 0.f, a1 = 0.f;
  for (int i = i0; i < i1; ++i) {
    int e = eid[i];
    float wt = expf(logits[e] - gm) * inv;
    uint32_t pk = *(const uint32_t*)(msg + (size_t)e * HID + lane * 2);
    a0 += wt * __uint_as_float(pk << 16);
    a1 += wt * __uint_as_float(pk & 0xFFFF0000u);
  }
  *(float2*)(out + (size_t)n * ND + lane * 2) = make_float2(a0, a1);
}

extern "C" void kernel_launch(void* const* d_in, const int* in_sizes, int n_in,
                              void* d_out, int out_size, void* d_ws, size_t ws_size,
                              hipStream_t stream) {
  const float* nf  = (const float*)d_in[0];
  const float* ef  = (const float*)d_in[1];
  const float* mW1 = (const float*)d_in[2];
  const float* mb1 = (const float*)d_in[3];
  const float* mW2 = (const float*)d_in[4];
  const float* mb2 = (const float*)d_in[5];
  const float* aW  = (const float*)d_in[6];
  // d_in[7] = a_b — unused (softmax is shift-invariant)
  const float* uW1 = (const float*)d_in[8];
  const float* ub1 = (const float*)d_in[9];
  const float* uW2 = (const float*)d_in[10];
  const float* ub2 = (const float*)d_in[11];
  const int*   ei  = (const int*)d_in[12];
  float* out = (float*)d_out;

  // ws layout (bytes):
  //   0          msg bf16 [NE*128]            153,600,000
  //   153600000  logits f32 [NE]                2,400,000
  //   156000000  pmax[1024] psum[1024] red          8,256
  //   156008256  W1p/W2p/U1p/U2p packed bf16      204,800
  //   156213056  rowptr/cnt/eid/bsum/boff       3,204,100
  //   159420416  nfb bf16 [NN*128]             25,600,000   -> total ~185MB
  char* ws = (char*)d_ws;
  uint16_t* msg = (uint16_t*)ws;
  float* logits = (float*)(ws + 153600000);
  float* pmax = (float*)(ws + 156000000);
  float* psum = pmax + 1024;
  float* red  = psum + 1024;
  short* W1p = (short*)(ws + 156008256);
  short* W2p = W1p + 36864;
  short* U1p = W2p + 16384;
  short* U2p = U1p + 32768;
  int* rowptr = (int*)(ws + 156213056);
  int* cnt    = rowptr + (NN + 1);
  int* eid    = cnt + NN;
  int* bsum   = eid + NE;
  int* boff   = bsum + 512;
  short* nfb  = (short*)(ws + 159420416);

  k_prep<<<400, 256, 0, stream>>>(mW1, mW2, uW1, uW2, W1p, W2p, U1p, U2p);
  k_prep_nf<<<2048, 256, 0, stream>>>(nf, nfb);
  k_zero_cnt<<<SCANB, 256, 0, stream>>>(cnt);
  k_hist<<<(NE + 255) / 256, 256, 0, stream>>>(ei, cnt);
  k_scan_bsum<<<SCANB, 256, 0, stream>>>(cnt, bsum);
  k_scan_boff<<<1, 512, 0, stream>>>(bsum, boff, rowptr);
  k_scan_final<<<SCANB, 256, 0, stream>>>(cnt, boff, rowptr);
  k_fill<<<(NE + 255) / 256, 256, 0, stream>>>(ei, cnt, eid);
  k_edge_mfma<<<(NE + 127) / 128, 256, 0, stream>>>(nfb, ef, W1p, mb1, W2p, mb2, aW, ei, msg, logits);
  k_red_p<<<1024, 256, 0, stream>>>(logits, pmax, psum);
  k_red_f<<<1, 256, 0, stream>>>(pmax, psum, red);
  k_agg<<<(NN + 3) / 4, 256, 0, stream>>>(msg, logits, rowptr, eid, red, out);
  k_node_mfma<<<(NN + 127) / 128, 256, 0, stream>>>(nf, nfb, out, U1p, ub1, U2p, ub2, out);
}

// Round 10
// 361.566 us; speedup vs baseline: 1.0733x; 1.0733x over previous
//
#include <hip/hip_runtime.h>
#include <hip/hip_bf16.h>
#include <stdint.h>

#define NN 100000
#define NE 600000
#define ND 128
#define ED 32
#define HID 128
#define SCANB 391  // ceil(NN/256)

using short8 = __attribute__((ext_vector_type(8))) short;
using f32x4  = __attribute__((ext_vector_type(4))) float;

// ---------- bf16 helpers (manual RNE, deterministic) ----------
__device__ __forceinline__ uint32_t f2bf(float f) {
  uint32_t u = __float_as_uint(f);
  return (u + 0x7FFFu + ((u >> 16) & 1u)) >> 16;
}
__device__ __forceinline__ short8 pack8(float4 a, float4 b) {
  short8 s;
  s[0] = (short)f2bf(a.x); s[1] = (short)f2bf(a.y);
  s[2] = (short)f2bf(a.z); s[3] = (short)f2bf(a.w);
  s[4] = (short)f2bf(b.x); s[5] = (short)f2bf(b.y);
  s[6] = (short)f2bf(b.z); s[7] = (short)f2bf(b.w);
  return s;
}

// ---------- weight pre-pack: frag-ordered bf16 ----------
__global__ __launch_bounds__(256) void k_prep(
    const float* __restrict__ W1, const float* __restrict__ W2,
    const float* __restrict__ uW1, const float* __restrict__ uW2,
    short* __restrict__ W1p, short* __restrict__ W2p,
    short* __restrict__ U1p, short* __restrict__ U2p) {
  int o = blockIdx.x * 256 + threadIdx.x;
  const float* src; short* dst; int rel;
  if (o < 36864)      { rel = o;         src = W1;  dst = W1p; }
  else if (o < 53248) { rel = o - 36864; src = W2;  dst = W2p; }
  else if (o < 86016) { rel = o - 53248; src = uW1; dst = U1p; }
  else                { rel = o - 86016; src = uW2; dst = U2p; }
  int j = rel & 7, c16 = (rel >> 3) & 15, g = (rel >> 7) & 3, nt = (rel >> 9) & 7, c = rel >> 12;
  int k = c * 32 + g * 8 + j, n = nt * 16 + c16;
  dst[rel] = (short)f2bf(src[k * 128 + n]);
}

// ---------- node features fp32 -> bf16 ----------
__global__ __launch_bounds__(256) void k_prep_nf(const float* __restrict__ nf,
                                                 short* __restrict__ nfb) {
  const int total = NN * ND / 8;
  for (int u = blockIdx.x * 256 + threadIdx.x; u < total; u += gridDim.x * 256) {
    const float* s = nf + (size_t)u * 8;
    float4 v0 = *(const float4*)s, v1 = *(const float4*)(s + 4);
    *(short8*)(nfb + (size_t)u * 8) = pack8(v0, v1);
  }
}

// ---------- edge MLP via MFMA (R8 192-row structure; msg/logits to CSR slots) ----------
__global__ __launch_bounds__(256, 2) void k_edge_mfma(
    const short* __restrict__ nfb, const float* __restrict__ ef,
    const short* __restrict__ W1p, const float* __restrict__ b1,
    const short* __restrict__ W2p, const float* __restrict__ b2,
    const float* __restrict__ aW, const int* __restrict__ ei,
    const int* __restrict__ perm,
    uint16_t* __restrict__ msg, float* __restrict__ logits) {
  __shared__ __align__(16) short sA[192 * 40];
  __shared__ __align__(16) short sB[4096];
  __shared__ __align__(16) short sH[192 * 136];
  __shared__ int sIdx[384];
  __shared__ int sPerm[192];

  const int tid = threadIdx.x;
  const int wv = tid >> 6, ln = tid & 63, cr = ln & 15, gp = ln >> 4;
  const int e0 = blockIdx.x * 192;   // grid exactly NE/192 = 3125
  const int wrow = wv * 48;

  if (tid < 192) {
    sIdx[tid] = ei[e0 + tid];
    sIdx[192 + tid] = ei[NE + e0 + tid];
    sPerm[tid] = perm[e0 + tid];
  }

  float bia[8], aWr[8], bia2[8];
#pragma unroll
  for (int nt = 0; nt < 8; ++nt) {
    bia[nt] = b1[nt * 16 + cr];
    bia2[nt] = b2[nt * 16 + cr];
    aWr[nt] = aW[nt * 16 + cr];
  }
  f32x4 acc[3][8];
#pragma unroll
  for (int mt = 0; mt < 3; ++mt)
#pragma unroll
    for (int nt = 0; nt < 8; ++nt)
      acc[mt][nt] = (f32x4){bia[nt], bia[nt], bia[nt], bia[nt]};
  __syncthreads();

  // layer 1: K = 288 (chunks 0-3: nfb[row], 4-7: nfb[col], 8: ef)
  for (int c = 0; c < 9; ++c) {
#pragma unroll
    for (int it = 0; it < 3; ++it) {
      int row = it * 64 + (tid >> 2), k8 = (tid & 3) * 8;
      if (c < 8) {
        const short* src = nfb + (size_t)sIdx[(c < 4 ? 0 : 192) + row] * ND +
                           (c & 3) * 32 + k8;
        *(short8*)&sA[row * 40 + k8] = *(const short8*)src;
      } else {
        const float* src = ef + (size_t)(e0 + row) * ED + k8;
        float4 v0 = *(const float4*)src, v1 = *(const float4*)(src + 4);
        *(short8*)&sA[row * 40 + k8] = pack8(v0, v1);
      }
    }
    {
      const short8* wsrc = (const short8*)(W1p + c * 4096);
      short8 t0 = wsrc[tid], t1 = wsrc[tid + 256];
      ((short8*)sB)[tid] = t0; ((short8*)sB)[tid + 256] = t1;
    }
    __syncthreads();
    short8 af[3];
#pragma unroll
    for (int mt = 0; mt < 3; ++mt)
      af[mt] = *(const short8*)&sA[(wrow + mt * 16 + cr) * 40 + gp * 8];
#pragma unroll
    for (int nt = 0; nt < 8; ++nt) {
      short8 bfr = *(const short8*)&sB[(nt * 4 + gp) * 128 + cr * 8];
#pragma unroll
      for (int mt = 0; mt < 3; ++mt)
        acc[mt][nt] = __builtin_amdgcn_mfma_f32_16x16x32_bf16(af[mt], bfr, acc[mt][nt], 0, 0, 0);
    }
    __syncthreads();
  }

  // relu -> sH (bf16)
#pragma unroll
  for (int mt = 0; mt < 3; ++mt)
#pragma unroll
    for (int nt = 0; nt < 8; ++nt)
#pragma unroll
      for (int rr = 0; rr < 4; ++rr)
        sH[(wrow + mt * 16 + gp * 4 + rr) * 136 + nt * 16 + cr] =
            (short)f2bf(fmaxf(acc[mt][nt][rr], 0.f));
  __syncthreads();

  // layer 2: K = 128
  f32x4 acc2[3][8];
#pragma unroll
  for (int mt = 0; mt < 3; ++mt)
#pragma unroll
    for (int nt = 0; nt < 8; ++nt)
      acc2[mt][nt] = (f32x4){bia2[nt], bia2[nt], bia2[nt], bia2[nt]};
  for (int c2 = 0; c2 < 4; ++c2) {
    {
      const short8* wsrc = (const short8*)(W2p + c2 * 4096);
      short8 t0 = wsrc[tid], t1 = wsrc[tid + 256];
      ((short8*)sB)[tid] = t0; ((short8*)sB)[tid + 256] = t1;
    }
    __syncthreads();
    short8 af[3];
#pragma unroll
    for (int mt = 0; mt < 3; ++mt)
      af[mt] = *(const short8*)&sH[(wrow + mt * 16 + cr) * 136 + c2 * 32 + gp * 8];
#pragma unroll
    for (int nt = 0; nt < 8; ++nt) {
      short8 bfr = *(const short8*)&sB[(nt * 4 + gp) * 128 + cr * 8];
#pragma unroll
      for (int mt = 0; mt < 3; ++mt)
        acc2[mt][nt] = __builtin_amdgcn_mfma_f32_16x16x32_bf16(af[mt], bfr, acc2[mt][nt], 0, 0, 0);
    }
    __syncthreads();
  }

  // attention logits -> CSR slot (reduce over the 16 col-lanes)
#pragma unroll
  for (int mt = 0; mt < 3; ++mt)
#pragma unroll
    for (int rr = 0; rr < 4; ++rr) {
      float p = 0.f;
#pragma unroll
      for (int nt = 0; nt < 8; ++nt) p += acc2[mt][nt][rr] * aWr[nt];
      p += __shfl_xor(p, 1, 64);
      p += __shfl_xor(p, 2, 64);
      p += __shfl_xor(p, 4, 64);
      p += __shfl_xor(p, 8, 64);
      if (cr == 0) logits[sPerm[wrow + mt * 16 + gp * 4 + rr]] = p;
    }

  // messages -> sH (bf16) -> 256B rows scattered to CSR slots
#pragma unroll
  for (int mt = 0; mt < 3; ++mt)
#pragma unroll
    for (int nt = 0; nt < 8; ++nt)
#pragma unroll
      for (int rr = 0; rr < 4; ++rr)
        sH[(wrow + mt * 16 + gp * 4 + rr) * 136 + nt * 16 + cr] =
            (short)f2bf(acc2[mt][nt][rr]);
  __syncthreads();
#pragma unroll
  for (int it = 0; it < 12; ++it) {
    int row = it * 16 + (tid >> 4), o8 = (tid & 15) * 8;
    *(short8*)(msg + (size_t)sPerm[row] * HID + o8) = *(const short8*)&sH[row * 136 + o8];
  }
}

// ---------- node update MLP via MFMA (+ residual): 192-tile, nfb bf16 reads ----------
__global__ __launch_bounds__(256, 2) void k_node_mfma(
    const float* __restrict__ nf, const short* __restrict__ nfb,
    const float* __restrict__ agg,
    const short* __restrict__ U1p, const float* __restrict__ b1,
    const short* __restrict__ U2p, const float* __restrict__ b2,
    float* __restrict__ out) {
  __shared__ __align__(16) short sA[192 * 40];
  __shared__ __align__(16) short sB[4096];
  __shared__ __align__(16) short sH[192 * 136];

  const int tid = threadIdx.x;
  const int wv = tid >> 6, ln = tid & 63, cr = ln & 15, gp = ln >> 4;
  const int n0 = blockIdx.x * 192;
  const int wrow = wv * 48;

  float bia[8], bia2[8];
#pragma unroll
  for (int nt = 0; nt < 8; ++nt) {
    bia[nt] = b1[nt * 16 + cr];
    bia2[nt] = b2[nt * 16 + cr];
  }
  f32x4 acc[3][8];
#pragma unroll
  for (int mt = 0; mt < 3; ++mt)
#pragma unroll
    for (int nt = 0; nt < 8; ++nt)
      acc[mt][nt] = (f32x4){bia[nt], bia[nt], bia[nt], bia[nt]};

  // layer 1: K = 256 (chunks 0-3: nfb bf16 direct, 4-7: agg fp32 -> pack)
  for (int c = 0; c < 8; ++c) {
#pragma unroll
    for (int it = 0; it < 3; ++it) {
      int row = it * 64 + (tid >> 2), k8 = (tid & 3) * 8;
      int n = n0 + row; if (n >= NN) n = NN - 1;
      if (c < 4) {
        *(short8*)&sA[row * 40 + k8] =
            *(const short8*)(nfb + (size_t)n * ND + c * 32 + k8);
      } else {
        const float* src = agg + (size_t)n * ND + (c - 4) * 32 + k8;
        float4 v0 = *(const float4*)src, v1 = *(const float4*)(src + 4);
        *(short8*)&sA[row * 40 + k8] = pack8(v0, v1);
      }
    }
    {
      const short8* wsrc = (const short8*)(U1p + c * 4096);
      short8 t0 = wsrc[tid], t1 = wsrc[tid + 256];
      ((short8*)sB)[tid] = t0; ((short8*)sB)[tid + 256] = t1;
    }
    __syncthreads();
    short8 af[3];
#pragma unroll
    for (int mt = 0; mt < 3; ++mt)
      af[mt] = *(const short8*)&sA[(wrow + mt * 16 + cr) * 40 + gp * 8];
#pragma unroll
    for (int nt = 0; nt < 8; ++nt) {
      short8 bfr = *(const short8*)&sB[(nt * 4 + gp) * 128 + cr * 8];
#pragma unroll
      for (int mt = 0; mt < 3; ++mt)
        acc[mt][nt] = __builtin_amdgcn_mfma_f32_16x16x32_bf16(af[mt], bfr, acc[mt][nt], 0, 0, 0);
    }
    __syncthreads();
  }

#pragma unroll
  for (int mt = 0; mt < 3; ++mt)
#pragma unroll
    for (int nt = 0; nt < 8; ++nt)
#pragma unroll
      for (int rr = 0; rr < 4; ++rr)
        sH[(wrow + mt * 16 + gp * 4 + rr) * 136 + nt * 16 + cr] =
            (short)f2bf(fmaxf(acc[mt][nt][rr], 0.f));
  __syncthreads();

  f32x4 acc2[3][8];
#pragma unroll
  for (int mt = 0; mt < 3; ++mt)
#pragma unroll
    for (int nt = 0; nt < 8; ++nt)
      acc2[mt][nt] = (f32x4){bia2[nt], bia2[nt], bia2[nt], bia2[nt]};
  for (int c2 = 0; c2 < 4; ++c2) {
    {
      const short8* wsrc = (const short8*)(U2p + c2 * 4096);
      short8 t0 = wsrc[tid], t1 = wsrc[tid + 256];
      ((short8*)sB)[tid] = t0; ((short8*)sB)[tid + 256] = t1;
    }
    __syncthreads();
    short8 af[3];
#pragma unroll
    for (int mt = 0; mt < 3; ++mt)
      af[mt] = *(const short8*)&sH[(wrow + mt * 16 + cr) * 136 + c2 * 32 + gp * 8];
#pragma unroll
    for (int nt = 0; nt < 8; ++nt) {
      short8 bfr = *(const short8*)&sB[(nt * 4 + gp) * 128 + cr * 8];
#pragma unroll
      for (int mt = 0; mt < 3; ++mt)
        acc2[mt][nt] = __builtin_amdgcn_mfma_f32_16x16x32_bf16(af[mt], bfr, acc2[mt][nt], 0, 0, 0);
    }
    __syncthreads();
  }

#pragma unroll
  for (int mt = 0; mt < 3; ++mt)
#pragma unroll
    for (int rr = 0; rr < 4; ++rr) {
      int n = n0 + wrow + mt * 16 + gp * 4 + rr;
      if (n < NN) {
#pragma unroll
        for (int nt = 0; nt < 8; ++nt) {
          int col = nt * 16 + cr;
          out[(size_t)n * ND + col] = acc2[mt][nt][rr] + nf[(size_t)n * ND + col];
        }
      }
    }
}

// ---------- fused online softmax reductions: (max,sum) pairs ----------
__device__ __forceinline__ void ms_combine(float& m, float& s, float m2, float s2) {
  float M = fmaxf(m, m2);
  s = s * expf(m - M) + s2 * expf(m2 - M);
  m = M;
}
__device__ __forceinline__ void ms_block_reduce(float& m, float& s) {
#pragma unroll
  for (int o = 1; o < 64; o <<= 1) {
    float m2 = __shfl_xor(m, o, 64), s2 = __shfl_xor(s, o, 64);
    ms_combine(m, s, m2, s2);
  }
  __shared__ float sm[4], ss[4];
  if ((threadIdx.x & 63) == 0) { sm[threadIdx.x >> 6] = m; ss[threadIdx.x >> 6] = s; }
  __syncthreads();
  m = sm[0]; s = ss[0];
  ms_combine(m, s, sm[1], ss[1]);
  ms_combine(m, s, sm[2], ss[2]);
  ms_combine(m, s, sm[3], ss[3]);
}
__global__ __launch_bounds__(256) void k_red_p(const float* __restrict__ logits,
                                               float* __restrict__ pmax,
                                               float* __restrict__ psum) {
  float m = -3.402823466e38f, s = 0.f;
  for (int i = blockIdx.x * 256 + threadIdx.x; i < NE; i += 1024 * 256) {
    float l = logits[i];
    if (l <= m) s += expf(l - m);
    else { s = s * expf(m - l) + 1.f; m = l; }
  }
  ms_block_reduce(m, s);
  if (threadIdx.x == 0) { pmax[blockIdx.x] = m; psum[blockIdx.x] = s; }
}
__global__ __launch_bounds__(256) void k_red_f(const float* __restrict__ pmax,
                                               const float* __restrict__ psum,
                                               float* __restrict__ red) {
  float m = pmax[threadIdx.x], s = psum[threadIdx.x];
  ms_combine(m, s, pmax[threadIdx.x + 256], psum[threadIdx.x + 256]);
  ms_combine(m, s, pmax[threadIdx.x + 512], psum[threadIdx.x + 512]);
  ms_combine(m, s, pmax[threadIdx.x + 768], psum[threadIdx.x + 768]);
  ms_block_reduce(m, s);
  if (threadIdx.x == 0) { red[0] = m; red[1] = 1.0f / s; }
}

// ---------- CSR build ----------
__global__ __launch_bounds__(256) void k_zero_cnt(int* __restrict__ cnt) {
  int i = blockIdx.x * 256 + threadIdx.x;
  if (i < NN) cnt[i] = 0;
}
__global__ __launch_bounds__(256) void k_hist(const int* __restrict__ ei,
                                              int* __restrict__ cnt) {
  int e = blockIdx.x * 256 + threadIdx.x;
  if (e < NE) atomicAdd(&cnt[ei[NE + e]], 1);
}
__global__ __launch_bounds__(256) void k_scan_bsum(const int* __restrict__ cnt,
                                                   int* __restrict__ bsum) {
  int i = blockIdx.x * 256 + threadIdx.x;
  int v = (i < NN) ? cnt[i] : 0;
#pragma unroll
  for (int s = 1; s < 64; s <<= 1) v += __shfl_xor(v, s, 64);
  __shared__ int sv[4];
  if ((threadIdx.x & 63) == 0) sv[threadIdx.x >> 6] = v;
  __syncthreads();
  if (threadIdx.x == 0) bsum[blockIdx.x] = sv[0] + sv[1] + sv[2] + sv[3];
}
__global__ __launch_bounds__(512) void k_scan_boff(const int* __restrict__ bsum,
                                                   int* __restrict__ boff,
                                                   int* __restrict__ rowptr) {
  __shared__ int s[512];
  int t = threadIdx.x;
  int v = (t < SCANB) ? bsum[t] : 0;
  s[t] = v;
  __syncthreads();
  for (int off = 1; off < 512; off <<= 1) {
    int u = (t >= off) ? s[t - off] : 0;
    __syncthreads();
    s[t] += u;
    __syncthreads();
  }
  if (t < SCANB) boff[t] = s[t] - v;  // exclusive
  if (t == 0) rowptr[NN] = NE;
}
__global__ __launch_bounds__(256) void k_scan_final(int* __restrict__ cnt,
                                                    const int* __restrict__ boff,
                                                    int* __restrict__ rowptr) {
  __shared__ int s[256];
  int b = blockIdx.x, t = threadIdx.x, i = b * 256 + t;
  int v = (i < NN) ? cnt[i] : 0;
  s[t] = v;
  __syncthreads();
  for (int off = 1; off < 256; off <<= 1) {
    int u = (t >= off) ? s[t - off] : 0;
    __syncthreads();
    s[t] += u;
    __syncthreads();
  }
  int excl = s[t] - v + boff[b];
  if (i < NN) { rowptr[i] = excl; cnt[i] = excl; }  // cnt becomes the fill cursor
}
// fill: perm[e] = CSR slot of edge e (inverse of the old eid)
__global__ __launch_bounds__(256) void k_fill(const int* __restrict__ ei,
                                              int* __restrict__ cursor,
                                              int* __restrict__ perm) {
  int e = blockIdx.x * 256 + threadIdx.x;
  if (e >= NE) return;
  int c = ei[NE + e];
  int pos = atomicAdd(&cursor[c], 1);
  perm[e] = pos;
}

// ---------- CSR aggregate: fully streaming (msg already in CSR order) ----------
__global__ __launch_bounds__(256) void k_agg(
    const uint16_t* __restrict__ msg, const float* __restrict__ logits,
    const int* __restrict__ rowptr, const float* __restrict__ red,
    float* __restrict__ out) {
  int n = blockIdx.x * 4 + (threadIdx.x >> 6);
  int lane = threadIdx.x & 63;
  if (n >= NN) return;
  float gm = red[0], inv = red[1];
  int i0 = rowptr[n], i1 = rowptr[n + 1];
  float a0 = 0.f, a1 = 0.f;
  for (int i = i0; i < i1; ++i) {
    float wt = expf(logits[i] - gm) * inv;
    uint32_t pk = *(const uint32_t*)(msg + (size_t)i * HID + lane * 2);
    a0 += wt * __uint_as_float(pk << 16);
    a1 += wt * __uint_as_float(pk & 0xFFFF0000u);
  }
  *(float2*)(out + (size_t)n * ND + lane * 2) = make_float2(a0, a1);
}

extern "C" void kernel_launch(void* const* d_in, const int* in_sizes, int n_in,
                              void* d_out, int out_size, void* d_ws, size_t ws_size,
                              hipStream_t stream) {
  const float* nf  = (const float*)d_in[0];
  const float* ef  = (const float*)d_in[1];
  const float* mW1 = (const float*)d_in[2];
  const float* mb1 = (const float*)d_in[3];
  const float* mW2 = (const float*)d_in[4];
  const float* mb2 = (const float*)d_in[5];
  const float* aW  = (const float*)d_in[6];
  // d_in[7] = a_b — unused (softmax is shift-invariant)
  const float* uW1 = (const float*)d_in[8];
  const float* ub1 = (const float*)d_in[9];
  const float* uW2 = (const float*)d_in[10];
  const float* ub2 = (const float*)d_in[11];
  const int*   ei  = (const int*)d_in[12];
  float* out = (float*)d_out;

  // ws layout (bytes):
  //   0          msg bf16 [NE*128] (CSR order) 153,600,000
  //   153600000  logits f32 [NE]   (CSR order)   2,400,000
  //   156000000  pmax[1024] psum[1024] red           8,256
  //   156008256  W1p/W2p/U1p/U2p packed bf16       204,800
  //   156213056  rowptr/cnt/perm/bsum/boff       3,204,100
  //   159420416  nfb bf16 [NN*128]              25,600,000   -> total ~185MB
  char* ws = (char*)d_ws;
  uint16_t* msg = (uint16_t*)ws;
  float* logits = (float*)(ws + 153600000);
  float* pmax = (float*)(ws + 156000000);
  float* psum = pmax + 1024;
  float* red  = psum + 1024;
  short* W1p = (short*)(ws + 156008256);
  short* W2p = W1p + 36864;
  short* U1p = W2p + 16384;
  short* U2p = U1p + 32768;
  int* rowptr = (int*)(ws + 156213056);
  int* cnt    = rowptr + (NN + 1);
  int* perm   = cnt + NN;
  int* bsum   = perm + NE;
  int* boff   = bsum + 512;
  short* nfb  = (short*)(ws + 159420416);

  k_prep<<<400, 256, 0, stream>>>(mW1, mW2, uW1, uW2, W1p, W2p, U1p, U2p);
  k_prep_nf<<<2048, 256, 0, stream>>>(nf, nfb);
  k_zero_cnt<<<SCANB, 256, 0, stream>>>(cnt);
  k_hist<<<(NE + 255) / 256, 256, 0, stream>>>(ei, cnt);
  k_scan_bsum<<<SCANB, 256, 0, stream>>>(cnt, bsum);
  k_scan_boff<<<1, 512, 0, stream>>>(bsum, boff, rowptr);
  k_scan_final<<<SCANB, 256, 0, stream>>>(cnt, boff, rowptr);
  k_fill<<<(NE + 255) / 256, 256, 0, stream>>>(ei, cnt, perm);
  k_edge_mfma<<<NE / 192, 256, 0, stream>>>(nfb, ef, W1p, mb1, W2p, mb2, aW, ei, perm, msg, logits);
  k_red_p<<<1024, 256, 0, stream>>>(logits, pmax, psum);
  k_red_f<<<1, 256, 0, stream>>>(pmax, psum, red);
  k_agg<<<(NN + 3) / 4, 256, 0, stream>>>(msg, logits, rowptr, red, out);
  k_node_mfma<<<(NN + 191) / 192, 256, 0, stream>>>(nf, nfb, out, U1p, ub1, U2p, ub2, out);
}